// Round 1
// baseline (1483.285 us; speedup 1.0000x reference)
//
#include <hip/hip_runtime.h>
#include <hip/hip_bf16.h>

// Problem constants (from reference)
#define NN 50000   // nodes
#define DI 128     // input features
#define DO 64      // output features
#define NE 800000  // edges per relation
#define NR 4       // relations

// ---------------------------------------------------------------------------
// GEMM: xw = x @ W_r  -> bf16 [NN, DO]
// Block = 256 (4 waves). Each wave computes 8 rows x 64 cols.
// W_r staged in LDS (128*64*4B = 32KB). x loads are wave-uniform -> s_load.
// ---------------------------------------------------------------------------
__global__ __launch_bounds__(256) void gemm_kernel(
    const float* __restrict__ x, const float* __restrict__ W,
    __hip_bfloat16* __restrict__ xwb)
{
    __shared__ float Wl[DI * DO];
    for (int i = threadIdx.x; i < DI * DO; i += 256) Wl[i] = W[i];
    __syncthreads();

    int wv   = __builtin_amdgcn_readfirstlane((int)(threadIdx.x >> 6));
    int lane = threadIdx.x & 63;
    int n0   = blockIdx.x * 32 + wv * 8;
    if (n0 >= NN) return;
    int nrows = NN - n0; if (nrows > 8) nrows = 8;

    if (nrows == 8) {
        const float* xr = x + (size_t)n0 * DI;   // wave-uniform base
        float acc[8] = {0.f,0.f,0.f,0.f,0.f,0.f,0.f,0.f};
        #pragma unroll 8
        for (int k = 0; k < DI; ++k) {
            float w = Wl[k * DO + lane];         // 1 LDS read feeds 8 FMAs
            #pragma unroll
            for (int rr = 0; rr < 8; ++rr)
                acc[rr] = fmaf(xr[(size_t)rr * DI + k], w, acc[rr]);
        }
        #pragma unroll
        for (int rr = 0; rr < 8; ++rr)
            xwb[(size_t)(n0 + rr) * DO + lane] = __float2bfloat16(acc[rr]);
    } else {
        for (int rr = 0; rr < nrows; ++rr) {
            const float* xr = x + (size_t)(n0 + rr) * DI;
            float acc = 0.f;
            for (int k = 0; k < DI; ++k)
                acc = fmaf(xr[k], Wl[k * DO + lane], acc);
            xwb[(size_t)(n0 + rr) * DO + lane] = __float2bfloat16(acc);
        }
    }
}

// ---------------------------------------------------------------------------
// Scatter: agg[row] += val * xw[col]   (COO SpMM, f32 atomics)
// One wave = 2 edges: lanes 0-31 edge A, 32-63 edge B.
// Each lane loads one bf16x2 (features 2l,2l+1) -> gather is 256B coalesced.
// ---------------------------------------------------------------------------
__global__ __launch_bounds__(256) void scatter_kernel(
    const __hip_bfloat16* __restrict__ xwb,
    const float* __restrict__ vals,
    const int*   __restrict__ rows,
    const int*   __restrict__ cols,
    float*       __restrict__ agg)
{
    const int nPairs = NE / 2;
    int gwave  = (blockIdx.x * 256 + threadIdx.x) >> 6;
    int half   = (threadIdx.x >> 5) & 1;
    int l32    = threadIdx.x & 31;
    int stride = gridDim.x * 4;
    const uint16_t* xw16 = reinterpret_cast<const uint16_t*>(xwb);

    for (int p = gwave; p < nPairs; p += stride) {
        int e   = 2 * p + half;
        int row = rows[e];
        int col = cols[e];
        float v = vals[e];
        uint32_t packed = *reinterpret_cast<const uint32_t*>(
            xw16 + ((size_t)col << 6) + 2 * l32);
        float f0 = __uint_as_float(packed << 16);
        float f1 = __uint_as_float(packed & 0xFFFF0000u);
        float* dst = agg + ((size_t)row << 6) + 2 * l32;
        atomicAdd(dst,     v * f0);
        atomicAdd(dst + 1, v * f1);
    }
}

// ---------------------------------------------------------------------------
// Accumulate: out (+)= relu(agg + b_r); also re-zero agg for next relation.
// ---------------------------------------------------------------------------
__global__ __launch_bounds__(256) void accum_kernel(
    float* __restrict__ agg, const float* __restrict__ b,
    float* __restrict__ out, int first)
{
    int i = blockIdx.x * 256 + threadIdx.x;
    if (i >= NN * DO) return;
    float v = agg[i] + b[i & (DO - 1)];
    agg[i] = 0.f;
    v = fmaxf(v, 0.f);
    out[i] = first ? v : (out[i] + v);
}

// ---------------------------------------------------------------------------
// Row-wise L2 normalize (in place). One wave per node row (64 features).
// ---------------------------------------------------------------------------
__global__ __launch_bounds__(256) void norm_kernel(float* __restrict__ out)
{
    int n    = (blockIdx.x * 256 + threadIdx.x) >> 6;
    int lane = threadIdx.x & 63;
    if (n >= NN) return;
    size_t idx = (size_t)n * DO + lane;
    float t = out[idx];
    float s = t * t;
    #pragma unroll
    for (int off = 32; off >= 1; off >>= 1) s += __shfl_xor(s, off);
    float norm = fmaxf(sqrtf(s), 1e-12f);
    out[idx] = t / norm;
}

extern "C" void kernel_launch(void* const* d_in, const int* in_sizes, int n_in,
                              void* d_out, int out_size, void* d_ws, size_t ws_size,
                              hipStream_t stream)
{
    const float* x    = (const float*)d_in[0];
    const float* W    = (const float*)d_in[1];
    const float* b    = (const float*)d_in[2];
    const float* vals = (const float*)d_in[3];
    const int*   rows = (const int*)d_in[4];
    const int*   cols = (const int*)d_in[5];
    float* out = (float*)d_out;

    // ws layout: [xwb bf16 NN*DO = 6.4MB][agg f32 NN*DO = 12.8MB] = 19.2MB
    __hip_bfloat16* xwb = (__hip_bfloat16*)d_ws;
    float* agg = (float*)((char*)d_ws + (size_t)NN * DO * sizeof(__hip_bfloat16));

    hipMemsetAsync(agg, 0, (size_t)NN * DO * sizeof(float), stream);

    for (int r = 0; r < NR; ++r) {
        gemm_kernel<<<dim3((NN + 31) / 32), dim3(256), 0, stream>>>(
            x, W + (size_t)r * DI * DO, xwb);
        scatter_kernel<<<dim3(2048), dim3(256), 0, stream>>>(
            xwb, vals + (size_t)r * NE, rows + (size_t)r * NE,
            cols + (size_t)r * NE, agg);
        accum_kernel<<<dim3((NN * DO + 255) / 256), dim3(256), 0, stream>>>(
            agg, b + (size_t)r * DO, out, r == 0);
    }
    norm_kernel<<<dim3((NN + 3) / 4), dim3(256), 0, stream>>>(out);
}

// Round 2
// 695.078 us; speedup vs baseline: 2.1340x; 2.1340x over previous
//
#include <hip/hip_runtime.h>
#include <hip/hip_bf16.h>

#define NN 50000   // nodes
#define DI 128     // input features
#define DO 64      // output features
#define NE 800000  // edges per relation
#define NR 4       // relations
#define SCAN_CHUNK 2048

// ---------------------------------------------------------------------------
// GEMM: xw[r] = x @ W_r -> bf16 [NN, DO]. blockIdx.y = relation.
// W_r staged in LDS (32KB). Each wave: 8 rows x 64 cols, x loads wave-uniform.
// ---------------------------------------------------------------------------
__global__ __launch_bounds__(256) void gemm_kernel(
    const float* __restrict__ x, const float* __restrict__ W,
    __hip_bfloat16* __restrict__ xwb)
{
    int r = blockIdx.y;
    const float* Wr = W + (size_t)r * DI * DO;
    __hip_bfloat16* xwr = xwb + (size_t)r * NN * DO;

    __shared__ float Wl[DI * DO];
    for (int i = threadIdx.x; i < DI * DO; i += 256) Wl[i] = Wr[i];
    __syncthreads();

    int wv   = __builtin_amdgcn_readfirstlane((int)(threadIdx.x >> 6));
    int lane = threadIdx.x & 63;
    int n0   = blockIdx.x * 32 + wv * 8;
    if (n0 >= NN) return;
    int nrows = NN - n0; if (nrows > 8) nrows = 8;

    if (nrows == 8) {
        const float* xr = x + (size_t)n0 * DI;
        float acc[8] = {0.f,0.f,0.f,0.f,0.f,0.f,0.f,0.f};
        #pragma unroll 8
        for (int k = 0; k < DI; ++k) {
            float w = Wl[k * DO + lane];
            #pragma unroll
            for (int rr = 0; rr < 8; ++rr)
                acc[rr] = fmaf(xr[(size_t)rr * DI + k], w, acc[rr]);
        }
        #pragma unroll
        for (int rr = 0; rr < 8; ++rr)
            xwr[(size_t)(n0 + rr) * DO + lane] = __float2bfloat16(acc[rr]);
    } else {
        for (int rr = 0; rr < nrows; ++rr) {
            const float* xr = x + (size_t)(n0 + rr) * DI;
            float acc = 0.f;
            for (int k = 0; k < DI; ++k)
                acc = fmaf(xr[k], Wl[k * DO + lane], acc);
            xwr[(size_t)(n0 + rr) * DO + lane] = __float2bfloat16(acc);
        }
    }
}

// ---------------------------------------------------------------------------
// CSR build step 1: histogram of row degrees. counts[r*NN + row]++.
// ---------------------------------------------------------------------------
__global__ __launch_bounds__(256) void hist_kernel(
    const int* __restrict__ rows, int* __restrict__ counts, int nRel)
{
    int g = blockIdx.x * 256 + threadIdx.x;
    int stride = gridDim.x * 256;
    int total = nRel * NE;
    for (; g < total; g += stride) {
        int r = g / NE;   // const divide -> magic mul
        atomicAdd(&counts[r * NN + rows[g]], 1);
    }
}

// ---------------------------------------------------------------------------
// Exclusive scan over nseg counts -> rowptr (+ duplicate into cursor).
// Three phases: block sums, single-thread scan of block sums, local scan.
// ---------------------------------------------------------------------------
__global__ __launch_bounds__(256) void scan1_kernel(
    const int* __restrict__ counts, int* __restrict__ bsum, int nseg)
{
    int base = blockIdx.x * SCAN_CHUNK;
    int t = 0;
    for (int j = threadIdx.x; j < SCAN_CHUNK; j += 256) {
        int idx = base + j;
        if (idx < nseg) t += counts[idx];
    }
    #pragma unroll
    for (int off = 32; off >= 1; off >>= 1) t += __shfl_xor(t, off);
    __shared__ int ws[4];
    if ((threadIdx.x & 63) == 0) ws[threadIdx.x >> 6] = t;
    __syncthreads();
    if (threadIdx.x == 0) bsum[blockIdx.x] = ws[0] + ws[1] + ws[2] + ws[3];
}

__global__ void scan2_kernel(int* __restrict__ bsum, int* __restrict__ rowptr,
                             int nblk, int nseg)
{
    if (blockIdx.x == 0 && threadIdx.x == 0) {
        int run = 0;
        for (int i = 0; i < nblk; ++i) { int v = bsum[i]; bsum[i] = run; run += v; }
        rowptr[nseg] = run;
    }
}

__global__ __launch_bounds__(256) void scan3_kernel(
    const int* __restrict__ counts, const int* __restrict__ bsum,
    int* __restrict__ rowptr, int* __restrict__ cursor, int nseg)
{
    int tid = threadIdx.x;
    int i0 = blockIdx.x * SCAN_CHUNK + tid * 8;
    int c[8]; int t = 0;
    #pragma unroll
    for (int j = 0; j < 8; ++j) {
        int idx = i0 + j;
        c[j] = (idx < nseg) ? counts[idx] : 0;
        t += c[j];
    }
    int lane = tid & 63, wv = tid >> 6;
    int inc = t;
    #pragma unroll
    for (int off = 1; off < 64; off <<= 1) {
        int u = __shfl_up(inc, off);
        if (lane >= off) inc += u;
    }
    __shared__ int wsum[4];
    if (lane == 63) wsum[wv] = inc;
    __syncthreads();
    int woff = 0;
    for (int w = 0; w < wv; ++w) woff += wsum[w];
    int p = bsum[blockIdx.x] + woff + (inc - t);
    #pragma unroll
    for (int j = 0; j < 8; ++j) {
        int idx = i0 + j;
        if (idx < nseg) { rowptr[idx] = p; cursor[idx] = p; }
        p += c[j];
    }
}

// ---------------------------------------------------------------------------
// CSR build step 2: place edges. csr[pos] = (col, val_bits).
// ---------------------------------------------------------------------------
__global__ __launch_bounds__(256) void fill_kernel(
    const int* __restrict__ rows, const int* __restrict__ cols,
    const float* __restrict__ vals, int* __restrict__ cursor,
    int2* __restrict__ csr, int nRel)
{
    int g = blockIdx.x * 256 + threadIdx.x;
    int stride = gridDim.x * 256;
    int total = nRel * NE;
    for (; g < total; g += stride) {
        int r = g / NE;
        int pos = atomicAdd(&cursor[r * NN + rows[g]], 1);
        csr[pos] = make_int2(cols[g], __float_as_int(vals[g]));
    }
}

// ---------------------------------------------------------------------------
// Fused SpMM over all 4 relations + bias + relu + sum + L2 normalize.
// One wave per node row, lane = feature. 4 relation chains interleaved
// for 4x memory-level parallelism. Edge meta loads are wave-uniform.
// ---------------------------------------------------------------------------
__global__ __launch_bounds__(256) void spmm_fused_kernel(
    const uint16_t* __restrict__ xw16, const int2* __restrict__ csr,
    const int* __restrict__ rowptr, const float* __restrict__ b,
    float* __restrict__ out)
{
    int n = __builtin_amdgcn_readfirstlane(
        (int)((blockIdx.x * 256 + threadIdx.x) >> 6));
    int lane = threadIdx.x & 63;
    if (n >= NN) return;

    int si[NR], ei[NR];
    #pragma unroll
    for (int r = 0; r < NR; ++r) {
        si[r] = rowptr[r * NN + n];
        ei[r] = rowptr[r * NN + n + 1];
    }
    float acc[NR] = {0.f, 0.f, 0.f, 0.f};
    bool any = true;
    while (any) {
        any = false;
        #pragma unroll
        for (int r = 0; r < NR; ++r) {
            if (si[r] < ei[r]) {
                int2 cv = csr[si[r]];
                si[r] += 1;
                uint32_t u = xw16[((size_t)(r * NN + cv.x) << 6) + lane];
                acc[r] = fmaf(__int_as_float(cv.y),
                              __uint_as_float(u << 16), acc[r]);
                any = true;
            }
        }
    }
    float total = 0.f;
    #pragma unroll
    for (int r = 0; r < NR; ++r)
        total += fmaxf(acc[r] + b[r * DO + lane], 0.f);
    float s2 = total * total;
    #pragma unroll
    for (int off = 32; off >= 1; off >>= 1) s2 += __shfl_xor(s2, off);
    out[(size_t)n * DO + lane] = total / fmaxf(sqrtf(s2), 1e-12f);
}

// ---------------------------------------------------------------------------
// Fallback path (small ws): single-relation SpMM accumulating into out.
// ---------------------------------------------------------------------------
__global__ __launch_bounds__(256) void spmm_single_kernel(
    const uint16_t* __restrict__ xw16, const int2* __restrict__ csr,
    const int* __restrict__ rowptr, const float* __restrict__ b,
    float* __restrict__ out, int first)
{
    int n = __builtin_amdgcn_readfirstlane(
        (int)((blockIdx.x * 256 + threadIdx.x) >> 6));
    int lane = threadIdx.x & 63;
    if (n >= NN) return;
    int s = rowptr[n], e = rowptr[n + 1];
    float acc = 0.f;
    for (int i = s; i < e; ++i) {
        int2 cv = csr[i];
        uint32_t u = xw16[((size_t)cv.x << 6) + lane];
        acc = fmaf(__int_as_float(cv.y), __uint_as_float(u << 16), acc);
    }
    float v = fmaxf(acc + b[lane], 0.f);
    size_t idx = (size_t)n * DO + lane;
    out[idx] = first ? v : (out[idx] + v);
}

__global__ __launch_bounds__(256) void norm_kernel(float* __restrict__ out)
{
    int n    = (blockIdx.x * 256 + threadIdx.x) >> 6;
    int lane = threadIdx.x & 63;
    if (n >= NN) return;
    size_t idx = (size_t)n * DO + lane;
    float t = out[idx];
    float s = t * t;
    #pragma unroll
    for (int off = 32; off >= 1; off >>= 1) s += __shfl_xor(s, off);
    out[idx] = t / fmaxf(sqrtf(s), 1e-12f);
}

extern "C" void kernel_launch(void* const* d_in, const int* in_sizes, int n_in,
                              void* d_out, int out_size, void* d_ws, size_t ws_size,
                              hipStream_t stream)
{
    const float* x    = (const float*)d_in[0];
    const float* W    = (const float*)d_in[1];
    const float* b    = (const float*)d_in[2];
    const float* vals = (const float*)d_in[3];
    const int*   rows = (const int*)d_in[4];
    const int*   cols = (const int*)d_in[5];
    float* out = (float*)d_out;
    char* ws = (char*)d_ws;

    // ---- fused layout (53.6 MB) ----
    const size_t F_XW = 0;                                   // 4*NN*DO*2 = 25.6MB
    const size_t F_CN = F_XW + (size_t)NR * NN * DO * 2;     // counts 800000
    const size_t F_RP = F_CN + (size_t)NR * NN * 4;          // rowptr 800016 (padded)
    const size_t F_CU = F_RP + ((size_t)NR * NN + 4) * 4;    // cursor 800000
    const size_t F_BS = F_CU + (size_t)NR * NN * 4;          // bsum 512
    const size_t F_CS = F_BS + 512;                          // csr 25.6MB
    const size_t F_NEED = F_CS + (size_t)NR * NE * 8;

    if (ws_size >= F_NEED) {
        __hip_bfloat16* xwb = (__hip_bfloat16*)(ws + F_XW);
        int*  counts = (int*)(ws + F_CN);
        int*  rowptr = (int*)(ws + F_RP);
        int*  cursor = (int*)(ws + F_CU);
        int*  bsum   = (int*)(ws + F_BS);
        int2* csr    = (int2*)(ws + F_CS);
        const int nseg = NR * NN;
        const int nblk = (nseg + SCAN_CHUNK - 1) / SCAN_CHUNK;

        hipMemsetAsync(counts, 0, (size_t)nseg * 4, stream);
        gemm_kernel<<<dim3((NN + 31) / 32, NR), dim3(256), 0, stream>>>(x, W, xwb);
        hist_kernel<<<dim3(2048), dim3(256), 0, stream>>>(rows, counts, NR);
        scan1_kernel<<<dim3(nblk), dim3(256), 0, stream>>>(counts, bsum, nseg);
        scan2_kernel<<<dim3(1), dim3(64), 0, stream>>>(bsum, rowptr, nblk, nseg);
        scan3_kernel<<<dim3(nblk), dim3(256), 0, stream>>>(counts, bsum, rowptr, cursor, nseg);
        fill_kernel<<<dim3(2048), dim3(256), 0, stream>>>(rows, cols, vals, cursor, csr, NR);
        spmm_fused_kernel<<<dim3((NN * 64 + 255) / 256), dim3(256), 0, stream>>>(
            (const uint16_t*)xwb, csr, rowptr, b, out);
    } else {
        // ---- sequential fallback (13.4 MB) ----
        const size_t S_XW = 0;                               // NN*DO*2 = 6.4MB
        const size_t S_CN = S_XW + (size_t)NN * DO * 2;      // counts 200000
        const size_t S_RP = S_CN + (size_t)NN * 4;           // rowptr 200016
        const size_t S_CU = S_RP + ((size_t)NN + 4) * 4;     // cursor 200000
        const size_t S_BS = S_CU + (size_t)NN * 4;           // bsum 512
        const size_t S_CS = S_BS + 512;                      // csr 6.4MB
        __hip_bfloat16* xwb = (__hip_bfloat16*)(ws + S_XW);
        int*  counts = (int*)(ws + S_CN);
        int*  rowptr = (int*)(ws + S_RP);
        int*  cursor = (int*)(ws + S_CU);
        int*  bsum   = (int*)(ws + S_BS);
        int2* csr    = (int2*)(ws + S_CS);
        const int nseg = NN;
        const int nblk = (nseg + SCAN_CHUNK - 1) / SCAN_CHUNK;

        for (int r = 0; r < NR; ++r) {
            hipMemsetAsync(counts, 0, (size_t)nseg * 4, stream);
            gemm_kernel<<<dim3((NN + 31) / 32, 1), dim3(256), 0, stream>>>(
                x, W + (size_t)r * DI * DO, xwb);
            hist_kernel<<<dim3(2048), dim3(256), 0, stream>>>(rows + (size_t)r * NE, counts, 1);
            scan1_kernel<<<dim3(nblk), dim3(256), 0, stream>>>(counts, bsum, nseg);
            scan2_kernel<<<dim3(1), dim3(64), 0, stream>>>(bsum, rowptr, nblk, nseg);
            scan3_kernel<<<dim3(nblk), dim3(256), 0, stream>>>(counts, bsum, rowptr, cursor, nseg);
            fill_kernel<<<dim3(2048), dim3(256), 0, stream>>>(
                rows + (size_t)r * NE, cols + (size_t)r * NE,
                vals + (size_t)r * NE, cursor, csr, 1);
            spmm_single_kernel<<<dim3((NN * 64 + 255) / 256), dim3(256), 0, stream>>>(
                (const uint16_t*)xwb, csr, rowptr, b + (size_t)r * DO, out, r == 0);
        }
        norm_kernel<<<dim3((NN * 64 + 255) / 256), dim3(256), 0, stream>>>(out);
    }
}